// Round 11
// baseline (77.640 us; speedup 1.0000x reference)
//
#include <hip/hip_runtime.h>
#include <hip/hip_bf16.h>

typedef __attribute__((ext_vector_type(8))) short bf16x8;
typedef __attribute__((ext_vector_type(4))) float f32x4;

constexpr int L     = 128;
constexpr int BK    = 256;           // f32 columns per tile
constexpr int GRID  = 256;           // gram: 1 block/CU (128 KB LDS)
constexpr int PITCH = BK * 2;        // 512 B per LDS/packed row-segment

__device__ inline float blo(unsigned w) { unsigned v = w << 16;          return __builtin_bit_cast(float, v); }
__device__ inline float bhi(unsigned w) { unsigned v = w & 0xffff0000u;  return __builtin_bit_cast(float, v); }

// ---- Phase 1: pure-stream pack. Chip-level sequential read of slots (f32),
// truncate to bf16, write tile-major pre-swizzled: packed[chunk][row][512B seg].
// One wave = one (row,chunk) segment: 1 KB linear read -> 512 B segment write.
__global__ __launch_bounds__(256)
void pack_kernel(const float* __restrict__ slots, char* __restrict__ packed, int D) {
    const size_t total  = (size_t)L * (D >> 2);          // float4 count: 8,388,608
    const size_t stride = (size_t)gridDim.x * 256;
    for (size_t i = (size_t)blockIdx.x * 256 + threadIdx.x; i < total; i += stride) {
        const float4 v = reinterpret_cast<const float4*>(slots)[i];
        const int row   = (int)(i >> 16);                // D/4 = 65536
        const int wf4   = (int)(i & 65535);
        const int chunk = wf4 >> 6;                      // 64 float4 per BK=256
        const int m     = wf4 & 63;
        const unsigned* f = reinterpret_cast<const unsigned*>(&v);
        uint2 w;
        w.x = __builtin_amdgcn_perm(f[1], f[0], 0x07060302u);   // lo=e0 hi=e1
        w.y = __builtin_amdgcn_perm(f[3], f[2], 0x07060302u);   // lo=e2 hi=e3
        const size_t seg  = (size_t)chunk * L + row;
        const int    byte = (m * 8) ^ ((row & 7) << 4);         // pre-swizzle
        *reinterpret_cast<uint2*>(packed + seg * PITCH + byte) = w;
    }
}

// ---- Phase 2: gram from packed tiles. Each tile = 64 KB CONTIGUOUS; staged by
// global_load_lds (linear dest == file layout == swizzled LDS image of R10).
__global__ __launch_bounds__(512, 2)
void gram_kernel(const char* __restrict__ packed, uint2* __restrict__ p16,
                 unsigned* __restrict__ cnt, int nChunks, int G) {
    __shared__ __align__(16) char lds[2][L * PITCH];   // 2 x 64 KB
    const int t    = threadIdx.x;        // 0..511
    const int wave = t >> 6;             // 0..7: wave owns rows [16w, 16w+16)
    const int lane = t & 63;

    if (blockIdx.x == 0 && t == 0) *cnt = 0;   // ticket for reduce_finalize

    f32x4 acc[8];
#pragma unroll
    for (int c = 0; c < 8; ++c) acc[c] = (f32x4)0.f;

    auto stage = [&](int buf, int tile) {
        const char* src = packed + (size_t)tile * (L * PITCH);
#pragma unroll
        for (int q = 0; q < 8; ++q) {
            const int off = (wave * 8 + q) * 1024;
            __builtin_amdgcn_global_load_lds(
                (const __attribute__((address_space(1))) unsigned*)(src + off + lane * 16),
                (__attribute__((address_space(3))) unsigned*)&lds[buf][off],
                16, 0, 0);
        }
    };
    // 8 bf16 of row `row`, local k = kk + (lane>>4)*8 .. +7: one ds_read_b128
    auto ldfrag = [&](int buf, int row, int kk) -> bf16x8 {
        int byte = row * PITCH + ((kk * 2 + ((lane >> 4) << 4)) ^ ((row & 7) << 4));
        return *reinterpret_cast<const bf16x8*>(&lds[buf][byte]);
    };

    stage(0, blockIdx.x);
    __syncthreads();

    int k = 0;
    for (int c = blockIdx.x; c < nChunks; c += G, ++k) {
        const int cur = k & 1;
        const bool more = (c + G < nChunks);
        if (more) stage(cur ^ 1, c + G);     // async DMA overlaps MFMA phase

#pragma unroll
        for (int kk = 0; kk < BK; kk += 32) {
            bf16x8 a = ldfrag(cur, wave * 16 + (lane & 15), kk);
#pragma unroll
            for (int cc = 0; cc < 8; ++cc) {
                bf16x8 b = ldfrag(cur, cc * 16 + (lane & 15), kk);
                acc[cc] = __builtin_amdgcn_mfma_f32_16x16x32_bf16(a, b, acc[cc], 0, 0, 0);
            }
        }
        __syncthreads();                     // drains gll vmcnt: next buf ready
    }

    // ---- coalesced bf16 partial writeout: uint2 slot j = cc*512 + t ----
    uint2* pb = p16 + (size_t)blockIdx.x * 4096;     // 32 KB per block
#pragma unroll
    for (int cc = 0; cc < 8; ++cc) {
        const unsigned* a = reinterpret_cast<const unsigned*>(&acc[cc]);
        uint2 w;
        w.x = __builtin_amdgcn_perm(a[1], a[0], 0x07060302u);   // lo=reg0 hi=reg1
        w.y = __builtin_amdgcn_perm(a[3], a[2], 0x07060302u);   // lo=reg2 hi=reg3
        pb[cc * 512 + t] = w;
    }
}

// 256 blocks x 256 threads; block owns 16 contiguous uint2-slots.
// Single-writer gram; last block (ticket) finalizes with LDS-staged gram.
__global__ __launch_bounds__(256)
void reduce_finalize(const uint2* __restrict__ p16, float* __restrict__ gram,
                     unsigned* __restrict__ cnt,
                     const float* __restrict__ temperature, float* __restrict__ out,
                     int G) {
    __shared__ __align__(16) float g[L * L];     // 64 KB (red tree aliases head)
    __shared__ float norms[L];
    __shared__ float wred[4];
    __shared__ unsigned ticket_s;
    const int t   = threadIdx.x;
    const int sl  = t & 15;              // slot within block
    const int sub = t >> 4;              // 0..15: b-range split
    const int j   = blockIdx.x * 16 + sl;        // uint2 slot 0..4095

    f32x4 s = (f32x4)0.f;
#pragma unroll 8
    for (int b = sub; b < G; b += 16) {
        const uint2 u = p16[(size_t)b * 4096 + j];
        s[0] += blo(u.x); s[1] += bhi(u.x);
        s[2] += blo(u.y); s[3] += bhi(u.y);
    }
    f32x4* red = reinterpret_cast<f32x4*>(g);    // [16][16]
    red[sub * 16 + sl] = s;
    __syncthreads();
    if (t < 16) {
        f32x4 s4 = red[t];
#pragma unroll
        for (int w = 1; w < 16; ++w) s4 += red[w * 16 + t];
        const int myj  = blockIdx.x * 16 + t;
        const int cc   = myj >> 9;
        const int tenc = myj & 511;
        const int wv = tenc >> 6, ln = tenc & 63;
        const int growb = wv * 16 + ((ln >> 4) << 2);
        const int gcol  = cc * 16 + (ln & 15);
#pragma unroll
        for (int q = 0; q < 4; ++q) gram[(growb + q) * L + gcol] = s4[q];
    }

    __syncthreads();
    if (t == 0) {
        __threadfence();
        ticket_s = atomicAdd(cnt, 1u);
    }
    __syncthreads();
    if (ticket_s != (unsigned)(gridDim.x - 1)) return;
    __threadfence();

    // ---------------- finalize (last block only) ----------------
#pragma unroll
    for (int q = 0; q < 16; ++q) {       // stage gram -> LDS (4096 float4)
        int i = t + 256 * q;
        *reinterpret_cast<float4*>(&g[i * 4]) =
            *reinterpret_cast<const float4*>(&gram[i * 4]);
    }
    __syncthreads();
    if (t < L) norms[t] = sqrtf(g[t * L + t]);
    __syncthreads();

    const float invT = 1.0f / temperature[0];
    const int r = t >> 1;                // row, 2 threads per row
    const int q = t & 1;
    const float ni = norms[r];

    float ps = 0.f;
    for (int jj = q; jj < L; jj += 2) {
        float sim = g[r * L + jj] / fmaxf(ni * norms[jj], 1e-6f);
        ps += __expf(sim * invT);
    }
    ps += __shfl_xor(ps, 1);
    const float rowsum = ps;

    float tot = 0.f;
    for (int jj = q; jj < L; jj += 2) {
        if (jj > r) {
            float logit = (g[r * L + jj] / fmaxf(ni * norms[jj], 1e-6f)) * invT;
            tot += -(logit - __logf(rowsum - __expf(logit))) * (float)(jj - r);
        }
    }
#pragma unroll
    for (int m = 1; m < 64; m <<= 1) tot += __shfl_xor(tot, m);
    if ((t & 63) == 0) wred[t >> 6] = tot;
    __syncthreads();
    if (t == 0)
        out[0] = (wred[0] + wred[1] + wred[2] + wred[3]) /
                 ((float)(L - 1) * (float)(L - 1) * 0.5f);
}

extern "C" void kernel_launch(void* const* d_in, const int* in_sizes, int n_in,
                              void* d_out, int out_size, void* d_ws, size_t ws_size,
                              hipStream_t stream) {
    const float* slots       = (const float*)d_in[0];
    const float* temperature = (const float*)d_in[1];
    float* out  = (float*)d_out;

    const int D = in_sizes[0] / L;                  // 262144
    const int nChunks = D / BK;                     // 1024
    int G = GRID;
    if (G > nChunks) G = nChunks;

    char*     packed = (char*)d_ws;                                  // 64 MB
    uint2*    p16    = (uint2*)(packed + (size_t)nChunks * L * PITCH);
    float*    gram   = (float*)((char*)p16 + (size_t)G * 32768);     // 64 KB
    unsigned* cnt    = (unsigned*)((char*)gram + (size_t)L * L * 4);

    pack_kernel<<<4096, 256, 0, stream>>>(slots, packed, D);
    gram_kernel<<<G, 512, 0, stream>>>(packed, p16, cnt, nChunks, G);
    reduce_finalize<<<256, 256, 0, stream>>>(p16, gram, cnt, temperature, out, G);
}

// Round 12
// 57.820 us; speedup vs baseline: 1.3428x; 1.3428x over previous
//
#include <hip/hip_runtime.h>
#include <hip/hip_bf16.h>

typedef __attribute__((ext_vector_type(8))) short bf16x8;
typedef __attribute__((ext_vector_type(4))) float f32x4;

constexpr int L    = 128;
constexpr int BK   = 128;            // f32 columns per tile
constexpr int GRID = 256;            // 1 block/CU (96 KB LDS)

// Region A: rows 0..63 as f32, [64][128] f32, unit=16B, unit XOR (row&15) swizzle.
// Region B: rows 64..127 as bf16, [64][128] bf16 (256 B pitch), byte XOR (row&7)<<4.
constexpr int A_BYTES = 64 * BK * 4;         // 32 KB
constexpr int B_BYTES = 64 * BK * 2;         // 16 KB
constexpr int BUF_BYTES = A_BYTES + B_BYTES; // 48 KB

__device__ inline float blo(unsigned w) { unsigned v = w << 16;          return __builtin_bit_cast(float, v); }
__device__ inline float bhi(unsigned w) { unsigned v = w & 0xffff0000u;  return __builtin_bit_cast(float, v); }

__global__ __launch_bounds__(512, 2)
void gram_kernel(const float* __restrict__ slots, uint2* __restrict__ p16,
                 unsigned* __restrict__ cnt, int D, int nChunks, int G) {
    __shared__ __align__(16) char lds[2][BUF_BYTES];
    const int t    = threadIdx.x;        // 0..511
    const int wave = t >> 6;             // 0..7: wave owns output rows [16w,16w+16)
    const int lane = t & 63;

    if (blockIdx.x == 0 && t == 0) *cnt = 0;   // ticket for reduce_finalize

    f32x4 acc[8];
#pragma unroll
    for (int c = 0; c < 8; ++c) acc[c] = (f32x4)0.f;

    float4 ld[4];

    // ---- path 1 (DMA queue): rows 0..63 via global_load_lds, f32, src-swizzled.
    // One glds instr covers 2 rows (32 lanes x 16B each); 4 instrs per wave.
    auto stageA = [&](int buf, int chunk) {
#pragma unroll
        for (int q = 0; q < 4; ++q) {
            const int r0  = wave * 8 + q * 2;            // rows r0, r0+1
            const int row = r0 + (lane >> 5);
            const int u   = (lane & 31) ^ (row & 15);    // source swizzle (16B units)
            const float* src = slots + (size_t)row * D + (size_t)chunk * BK + u * 4;
            __builtin_amdgcn_global_load_lds(
                (const __attribute__((address_space(1))) unsigned*)src,
                (__attribute__((address_space(3))) unsigned*)&lds[buf][r0 * 512],
                16, 0, 0);
        }
    };
    // ---- path 2 (VGPR-return queue): rows 64..127 via register loads -> bf16.
    auto issueB = [&](int chunk) {
#pragma unroll
        for (int q = 0; q < 4; ++q) {
            int idx  = t + 512 * q;      // 0..2047
            int row  = 64 + (idx >> 5);
            int col4 = idx & 31;
            ld[q] = *reinterpret_cast<const float4*>(
                slots + (size_t)row * D + (size_t)chunk * BK + col4 * 4);
        }
    };
    auto commitB = [&](int buf) {
#pragma unroll
        for (int q = 0; q < 4; ++q) {
            int idx  = t + 512 * q;
            int rb   = idx >> 5;         // 0..63 (row-64)
            int col4 = idx & 31;
            const unsigned* f = reinterpret_cast<const unsigned*>(&ld[q]);
            uint2 w;
            w.x = __builtin_amdgcn_perm(f[1], f[0], 0x07060302u);   // lo=e0 hi=e1
            w.y = __builtin_amdgcn_perm(f[3], f[2], 0x07060302u);   // lo=e2 hi=e3
            int byte = (col4 * 8) ^ ((rb & 7) << 4);
            *reinterpret_cast<uint2*>(&lds[buf][A_BYTES + rb * 256 + byte]) = w;
        }
    };
    // fragment from A (row 0..63): two f32 b128 reads + perm-truncate to bf16
    auto ldfragA = [&](int buf, int row, int kk) -> bf16x8 {
        const int u0 = (kk >> 2) + ((lane >> 4) << 1);
        const int p0 = u0 ^ (row & 15);
        const int p1 = (u0 + 1) ^ (row & 15);
        const char* base = &lds[buf][row * 512];
        const f32x4 f0 = *reinterpret_cast<const f32x4*>(base + p0 * 16);
        const f32x4 f1 = *reinterpret_cast<const f32x4*>(base + p1 * 16);
        const unsigned* a = reinterpret_cast<const unsigned*>(&f0);
        const unsigned* b = reinterpret_cast<const unsigned*>(&f1);
        union { bf16x8 v; unsigned w[4]; } r;
        r.w[0] = __builtin_amdgcn_perm(a[1], a[0], 0x07060302u);
        r.w[1] = __builtin_amdgcn_perm(a[3], a[2], 0x07060302u);
        r.w[2] = __builtin_amdgcn_perm(b[1], b[0], 0x07060302u);
        r.w[3] = __builtin_amdgcn_perm(b[3], b[2], 0x07060302u);
        return r.v;
    };
    // fragment from B (row 64..127): one bf16 b128 read
    auto ldfragB = [&](int buf, int row, int kk) -> bf16x8 {
        const int rb = row - 64;
        int byte = A_BYTES + rb * 256 + ((kk * 2 + ((lane >> 4) << 4)) ^ ((rb & 7) << 4));
        return *reinterpret_cast<const bf16x8*>(&lds[buf][byte]);
    };

    stageA(0, blockIdx.x);
    issueB(blockIdx.x);
    commitB(0);
    __syncthreads();

    int k = 0;
    for (int c = blockIdx.x; c < nChunks; c += G, ++k) {
        const int cur = k & 1;
        const bool more = (c + G < nChunks);
        if (more) { stageA(cur ^ 1, c + G); issueB(c + G); }   // both queues in flight

        const int rowa = wave * 16 + (lane & 15);
#pragma unroll
        for (int kk = 0; kk < BK; kk += 32) {
            bf16x8 a = (wave < 4) ? ldfragA(cur, rowa, kk) : ldfragB(cur, rowa, kk);
#pragma unroll
            for (int cc = 0; cc < 8; ++cc) {
                const int rowb = cc * 16 + (lane & 15);
                bf16x8 b = (cc < 4) ? ldfragA(cur, rowb, kk) : ldfragB(cur, rowb, kk);
                acc[cc] = __builtin_amdgcn_mfma_f32_16x16x32_bf16(a, b, acc[cc], 0, 0, 0);
            }
        }

        if (more) commitB(cur ^ 1);
        __syncthreads();                 // drains reg loads + glds; next buf ready
    }

    // ---- coalesced bf16 partial writeout: uint2 slot j = cc*512 + t ----
    uint2* pb = p16 + (size_t)blockIdx.x * 4096;     // 32 KB per block
#pragma unroll
    for (int cc = 0; cc < 8; ++cc) {
        const unsigned* a = reinterpret_cast<const unsigned*>(&acc[cc]);
        uint2 w;
        w.x = __builtin_amdgcn_perm(a[1], a[0], 0x07060302u);   // lo=reg0 hi=reg1
        w.y = __builtin_amdgcn_perm(a[3], a[2], 0x07060302u);   // lo=reg2 hi=reg3
        pb[cc * 512 + t] = w;
    }
}

// 256 blocks x 256 threads; block owns 16 contiguous uint2-slots.
// Single-writer gram; last block (ticket) finalizes with LDS-staged gram.
__global__ __launch_bounds__(256)
void reduce_finalize(const uint2* __restrict__ p16, float* __restrict__ gram,
                     unsigned* __restrict__ cnt,
                     const float* __restrict__ temperature, float* __restrict__ out,
                     int G) {
    __shared__ __align__(16) float g[L * L];     // 64 KB (red tree aliases head)
    __shared__ float norms[L];
    __shared__ float wred[4];
    __shared__ unsigned ticket_s;
    const int t   = threadIdx.x;
    const int sl  = t & 15;              // slot within block
    const int sub = t >> 4;              // 0..15: b-range split
    const int j   = blockIdx.x * 16 + sl;        // uint2 slot 0..4095

    f32x4 s = (f32x4)0.f;
#pragma unroll 8
    for (int b = sub; b < G; b += 16) {
        const uint2 u = p16[(size_t)b * 4096 + j];
        s[0] += blo(u.x); s[1] += bhi(u.x);
        s[2] += blo(u.y); s[3] += bhi(u.y);
    }
    f32x4* red = reinterpret_cast<f32x4*>(g);    // [16][16]
    red[sub * 16 + sl] = s;
    __syncthreads();
    if (t < 16) {
        f32x4 s4 = red[t];
#pragma unroll
        for (int w = 1; w < 16; ++w) s4 += red[w * 16 + t];
        const int myj  = blockIdx.x * 16 + t;
        const int cc   = myj >> 9;
        const int tenc = myj & 511;
        const int wv = tenc >> 6, ln = tenc & 63;
        const int growb = wv * 16 + ((ln >> 4) << 2);
        const int gcol  = cc * 16 + (ln & 15);
#pragma unroll
        for (int q = 0; q < 4; ++q) gram[(growb + q) * L + gcol] = s4[q];
    }

    __syncthreads();
    if (t == 0) {
        __threadfence();
        ticket_s = atomicAdd(cnt, 1u);
    }
    __syncthreads();
    if (ticket_s != (unsigned)(gridDim.x - 1)) return;
    __threadfence();

    // ---------------- finalize (last block only) ----------------
#pragma unroll
    for (int q = 0; q < 16; ++q) {       // stage gram -> LDS (4096 float4)
        int i = t + 256 * q;
        *reinterpret_cast<float4*>(&g[i * 4]) =
            *reinterpret_cast<const float4*>(&gram[i * 4]);
    }
    __syncthreads();
    if (t < L) norms[t] = sqrtf(g[t * L + t]);
    __syncthreads();

    const float invT = 1.0f / temperature[0];
    const int r = t >> 1;                // row, 2 threads per row
    const int q = t & 1;
    const float ni = norms[r];

    float ps = 0.f;
    for (int jj = q; jj < L; jj += 2) {
        float sim = g[r * L + jj] / fmaxf(ni * norms[jj], 1e-6f);
        ps += __expf(sim * invT);
    }
    ps += __shfl_xor(ps, 1);
    const float rowsum = ps;

    float tot = 0.f;
    for (int jj = q; jj < L; jj += 2) {
        if (jj > r) {
            float logit = (g[r * L + jj] / fmaxf(ni * norms[jj], 1e-6f)) * invT;
            tot += -(logit - __logf(rowsum - __expf(logit))) * (float)(jj - r);
        }
    }
#pragma unroll
    for (int m = 1; m < 64; m <<= 1) tot += __shfl_xor(tot, m);
    if ((t & 63) == 0) wred[t >> 6] = tot;
    __syncthreads();
    if (t == 0)
        out[0] = (wred[0] + wred[1] + wred[2] + wred[3]) /
                 ((float)(L - 1) * (float)(L - 1) * 0.5f);
}

extern "C" void kernel_launch(void* const* d_in, const int* in_sizes, int n_in,
                              void* d_out, int out_size, void* d_ws, size_t ws_size,
                              hipStream_t stream) {
    const float* slots       = (const float*)d_in[0];
    const float* temperature = (const float*)d_in[1];
    float* out  = (float*)d_out;

    const int D = in_sizes[0] / L;                  // 262144
    const int nChunks = D / BK;                     // 2048
    int G = GRID;
    if (G > nChunks) G = nChunks;

    uint2*    p16  = (uint2*)d_ws;                                 // G*32 KB = 8 MB
    float*    gram = (float*)((char*)d_ws + (size_t)G * 32768);    // 64 KB
    unsigned* cnt  = (unsigned*)((char*)gram + (size_t)L * L * 4);

    gram_kernel<<<G, 512, 0, stream>>>(slots, p16, cnt, D, nChunks, G);
    reduce_finalize<<<256, 256, 0, stream>>>(p16, gram, cnt, temperature, out, G);
}